// Round 1
// baseline (153.740 us; speedup 1.0000x reference)
//
#include <hip/hip_runtime.h>

typedef __attribute__((ext_vector_type(8))) short short8;
typedef __attribute__((ext_vector_type(4))) float f32x4;

constexpr int Bn = 4, Cn = 192, Tn = 2048, Hn = 4, HD = 48;
constexpr float RSQRT_HD = 0.14433756729740643f;  // 1/sqrt(48)

__device__ inline unsigned short f2bf(float f) {
  unsigned int u = __builtin_bit_cast(unsigned int, f);
  return (unsigned short)((u + 0x7FFFu + ((u >> 16) & 1u)) >> 16);
}
__device__ inline float bf2f(unsigned short h) {
  unsigned int u = ((unsigned int)h) << 16;
  return __builtin_bit_cast(float, u);
}
__device__ inline f32x4 mfma16(short8 a, short8 b, f32x4 c) {
  return __builtin_amdgcn_mfma_f32_16x16x32_bf16(a, b, c, 0, 0, 0);
}

// ---------------------------------------------------------------- transpose x
// x[b][c][t] f32  ->  XT[b][t][c] bf16
__global__ __launch_bounds__(256) void transpose_x(const float* __restrict__ x,
                                                   short* __restrict__ xt) {
  __shared__ short tile[32][40];
  int t0 = blockIdx.x * 32, c0 = blockIdx.y * 32, b = blockIdx.z;
  int tid = threadIdx.x;
  int row = tid >> 3, q = tid & 7;
  float4 v = *(const float4*)(x + ((size_t)(b * Cn + c0 + row)) * Tn + t0 + q * 4);
  tile[row][q * 4 + 0] = (short)f2bf(v.x);
  tile[row][q * 4 + 1] = (short)f2bf(v.y);
  tile[row][q * 4 + 2] = (short)f2bf(v.z);
  tile[row][q * 4 + 3] = (short)f2bf(v.w);
  __syncthreads();
  ushort4 pk;
  pk.x = (unsigned short)tile[q * 4 + 0][row];
  pk.y = (unsigned short)tile[q * 4 + 1][row];
  pk.z = (unsigned short)tile[q * 4 + 2][row];
  pk.w = (unsigned short)tile[q * 4 + 3][row];
  *(ushort4*)(xt + ((size_t)(b * Tn + t0 + row)) * Cn + c0 + q * 4) = pk;
}

// ---------------------------------------------------------------- weights
// W[k][n] f32 -> WT[j][n][k] bf16  (j = 0..3 : Wq, Wk, Wc, Wp)
__global__ void prep_w(const float* __restrict__ Wq, const float* __restrict__ Wk,
                       const float* __restrict__ Wc, const float* __restrict__ Wp,
                       short* __restrict__ WT) {
  int n = blockIdx.x, j = blockIdx.y, k = threadIdx.x;
  const float* W = (j == 0) ? Wq : (j == 1) ? Wk : (j == 2) ? Wc : Wp;
  WT[((size_t)j * Cn + n) * Cn + k] = (short)f2bf(W[(size_t)k * Cn + n]);
}

// ---------------------------------------------------------------- GEMM 192xK192
// Out[n][t] = sum_k WT[n][k] * Bsrc[b][t][k] + bias[n]  (n-tile 64 x t-tile 128)
// MODE 0: bf16 c-major Out[b][192][2048]
// MODE 1: bf16 t-major Out[b][2048][192]
// MODE 2: f32 c-major + residual Xres (final output)
template <int MODE>
__global__ __launch_bounds__(256) void gemm192(const short* __restrict__ Awt,
                                               const float* __restrict__ bias,
                                               const short* __restrict__ Bsrc,
                                               void* __restrict__ OutP,
                                               const float* __restrict__ Xres) {
  constexpr int LDK = 200;  // 192 + 8 pad (keeps 16B alignment, breaks pow2 stride)
  __shared__ short As[64 * LDK];
  __shared__ short Bs[128 * LDK];
  int tt = blockIdx.x, nt = blockIdx.y, b = blockIdx.z;
  int n0 = nt * 64, t0 = tt * 128;
  int tid = threadIdx.x, w = tid >> 6, l = tid & 63;
  int g16 = l >> 4, c16 = l & 15;

  for (int idx = tid; idx < 4608; idx += 256) {
    if (idx < 1536) {
      int row = idx / 24, ch = idx % 24;
      *(float4*)(&As[row * LDK + ch * 8]) =
          *(const float4*)(Awt + ((size_t)(n0 + row)) * Cn + ch * 8);
    } else {
      int j = idx - 1536;
      int row = j / 24, ch = j % 24;
      *(float4*)(&Bs[row * LDK + ch * 8]) =
          *(const float4*)(Bsrc + ((size_t)(b * Tn + t0 + row)) * Cn + ch * 8);
    }
  }
  __syncthreads();

  f32x4 acc[4][2];
#pragma unroll
  for (int m = 0; m < 4; ++m)
#pragma unroll
    for (int n = 0; n < 2; ++n) acc[m][n] = (f32x4){0.f, 0.f, 0.f, 0.f};

#pragma unroll
  for (int kk = 0; kk < 6; ++kk) {
    short8 af[4], bf[2];
#pragma unroll
    for (int m = 0; m < 4; ++m)
      af[m] = *(const short8*)(&As[(m * 16 + c16) * LDK + kk * 32 + g16 * 8]);
#pragma unroll
    for (int n = 0; n < 2; ++n)
      bf[n] = *(const short8*)(&Bs[(w * 32 + n * 16 + c16) * LDK + kk * 32 + g16 * 8]);
#pragma unroll
    for (int m = 0; m < 4; ++m)
#pragma unroll
      for (int n = 0; n < 2; ++n) acc[m][n] = mfma16(af[m], bf[n], acc[m][n]);
  }

#pragma unroll
  for (int m = 0; m < 4; ++m)
#pragma unroll
    for (int n = 0; n < 2; ++n) {
      int nrow = n0 + m * 16 + g16 * 4;
      int tcol = t0 + w * 32 + n * 16 + c16;
      if constexpr (MODE == 0) {
        short* O = (short*)OutP;
#pragma unroll
        for (int r = 0; r < 4; ++r)
          O[((size_t)(b * Cn + nrow + r)) * Tn + tcol] =
              (short)f2bf(acc[m][n][r] + bias[nrow + r]);
      } else if constexpr (MODE == 1) {
        short* O = (short*)OutP;
        ushort4 pk;
        pk.x = f2bf(acc[m][n][0] + bias[nrow + 0]);
        pk.y = f2bf(acc[m][n][1] + bias[nrow + 1]);
        pk.z = f2bf(acc[m][n][2] + bias[nrow + 2]);
        pk.w = f2bf(acc[m][n][3] + bias[nrow + 3]);
        *(ushort4*)(O + ((size_t)(b * Tn + tcol)) * Cn + nrow) = pk;
      } else {
        float* O = (float*)OutP;
#pragma unroll
        for (int r = 0; r < 4; ++r) {
          size_t i = ((size_t)(b * Cn + nrow + r)) * Tn + tcol;
          O[i] = acc[m][n][r] + bias[nrow + r] + Xres[i];
        }
      }
    }
}

// ---------------------------------------------------------------- decay scalar
// g[b][h][t] = 0.25 * sum_f (f+1)*sigmoid( (xt@Wd + bd)[b,t,h*4+f] )
__global__ __launch_bounds__(256) void decay_g(const short* __restrict__ xt,
                                               const float* __restrict__ Wd,
                                               const float* __restrict__ bd,
                                               float* __restrict__ gout) {
  int idx = blockIdx.x * 256 + threadIdx.x;
  int b = idx >> 11, t = idx & 2047;
  const short* xr = xt + ((size_t)(b * Tn + t)) * Cn;
  float d[16];
#pragma unroll
  for (int n = 0; n < 16; ++n) d[n] = bd[n];
  for (int k = 0; k < Cn; k += 8) {
    short8 xv8 = *(const short8*)(xr + k);
#pragma unroll
    for (int j = 0; j < 8; ++j) {
      float xv = bf2f((unsigned short)xv8[j]);
#pragma unroll
      for (int n = 0; n < 16; ++n) d[n] += xv * Wd[(k + j) * 16 + n];
    }
  }
#pragma unroll
  for (int h = 0; h < 4; ++h) {
    float gsum = 0.f;
#pragma unroll
    for (int f = 0; f < 4; ++f) {
      float s = 1.f / (1.f + __expf(-d[h * 4 + f]));
      gsum += (float)(f + 1) * s;
    }
    gout[((size_t)(b * 4 + h)) * Tn + t] = 0.25f * gsum;
  }
}

// ---------------------------------------------------------------- fused attention
// Qt,Kt: [b][t][192] bf16 (t-major); Vc: [b][192][2048] bf16 (c-major)
// Rt out: [b][s][192] bf16 (t-major), rows n = h*48+c
__global__ __launch_bounds__(256) void attn(const short* __restrict__ Qt,
                                            const short* __restrict__ Kt,
                                            const short* __restrict__ Vc,
                                            const float* __restrict__ gbuf,
                                            short* __restrict__ Rt) {
  __shared__ short Kb[64][80];
  __shared__ short Vb[48][80];
  __shared__ short Pl[4][16][80];
  int s0 = blockIdx.x * 64;
  int bh = blockIdx.y;
  int b = bh >> 2, h = bh & 3;
  int tid = threadIdx.x, w = tid >> 6, l = tid & 63;
  int g16 = l >> 4, c16 = l & 15;

  // zero the c-pad (cols 48..63) of Kb once; staging only writes cols 0..47
  float4 z4;
  z4.x = z4.y = z4.z = z4.w = 0.f;
  for (int idx = tid; idx < 128; idx += 256) {
    int row = idx >> 1, part = idx & 1;
    *(float4*)(&Kb[row][48 + part * 8]) = z4;
  }
  // stage Q (this block's 64 queries) into Kb, read fragments, then reuse Kb
  for (int idx = tid; idx < 384; idx += 256) {
    int row = idx / 6, ch = idx % 6;
    *(float4*)(&Kb[row][ch * 8]) =
        *(const float4*)(Qt + ((size_t)(b * Tn + s0 + row)) * Cn + h * HD + ch * 8);
  }
  __syncthreads();
  short8 qf[2];
  qf[0] = *(const short8*)(&Kb[w * 16 + c16][g16 * 8]);
  qf[1] = *(const short8*)(&Kb[w * 16 + c16][32 + g16 * 8]);
  __syncthreads();

  int s_lane = s0 + w * 16 + c16;
  float g_lane = gbuf[((size_t)(b * 4 + h)) * Tn + s_lane];
  float m_run = -3.0e38f, l_run = 0.f;
  f32x4 acc[3];
#pragma unroll
  for (int cs = 0; cs < 3; ++cs) acc[cs] = (f32x4){0.f, 0.f, 0.f, 0.f};

  for (int t0 = 0; t0 < Tn; t0 += 64) {
    for (int idx = tid; idx < 768; idx += 256) {
      if (idx < 384) {
        int row = idx / 6, ch = idx % 6;
        *(float4*)(&Kb[row][ch * 8]) =
            *(const float4*)(Kt + ((size_t)(b * Tn + t0 + row)) * Cn + h * HD + ch * 8);
      } else {
        int j = idx - 384, row = j >> 3, ch = j & 7;
        *(float4*)(&Vb[row][ch * 8]) =
            *(const float4*)(Vc + ((size_t)(b * Cn + h * HD + row)) * Tn + t0 + ch * 8);
      }
    }
    __syncthreads();

    // S = K_tile^T . Q  : D[t_local, s]  (4 m-subtiles x 2 k-steps)
    f32x4 sacc[4];
#pragma unroll
    for (int m = 0; m < 4; ++m) sacc[m] = (f32x4){0.f, 0.f, 0.f, 0.f};
#pragma unroll
    for (int kk = 0; kk < 2; ++kk)
#pragma unroll
      for (int m = 0; m < 4; ++m) {
        short8 af = *(const short8*)(&Kb[m * 16 + c16][kk * 32 + g16 * 8]);
        sacc[m] = mfma16(af, qf[kk], sacc[m]);
      }

    // scale + decay bias + diagonal mask; online softmax (per-lane column)
    float sv[16];
    float tmax = -3.0e38f;
#pragma unroll
    for (int m = 0; m < 4; ++m)
#pragma unroll
      for (int r = 0; r < 4; ++r) {
        int tg = t0 + m * 16 + g16 * 4 + r;
        float v = sacc[m][r] * RSQRT_HD - g_lane * fabsf((float)(tg - s_lane));
        if (tg == s_lane) v = -100.f;
        sv[m * 4 + r] = v;
        tmax = fmaxf(tmax, v);
      }
    tmax = fmaxf(tmax, __shfl_xor(tmax, 16));
    tmax = fmaxf(tmax, __shfl_xor(tmax, 32));
    float m_new = fmaxf(m_run, tmax);
    float alpha = __expf(m_run - m_new);
    float tsum = 0.f;
#pragma unroll
    for (int i = 0; i < 16; ++i) {
      sv[i] = __expf(sv[i] - m_new);
      tsum += sv[i];
    }
    tsum += __shfl_xor(tsum, 16);
    tsum += __shfl_xor(tsum, 32);
    l_run = l_run * alpha + tsum;
    m_run = m_new;
#pragma unroll
    for (int cs = 0; cs < 3; ++cs) {
      acc[cs][0] *= alpha;
      acc[cs][1] *= alpha;
      acc[cs][2] *= alpha;
      acc[cs][3] *= alpha;
    }

    // P -> wave-private LDS (col-major [s][t]) to form PV B-fragments
#pragma unroll
    for (int m = 0; m < 4; ++m) {
      unsigned int u0 =
          (unsigned int)f2bf(sv[m * 4 + 0]) | ((unsigned int)f2bf(sv[m * 4 + 1]) << 16);
      unsigned int u1 =
          (unsigned int)f2bf(sv[m * 4 + 2]) | ((unsigned int)f2bf(sv[m * 4 + 3]) << 16);
      *(unsigned int*)(&Pl[w][c16][m * 16 + g16 * 4]) = u0;
      *(unsigned int*)(&Pl[w][c16][m * 16 + g16 * 4 + 2]) = u1;
    }
    asm volatile("s_waitcnt lgkmcnt(0)" ::: "memory");

    // O += V_tile . P   (3 c-subtiles x 2 k-steps over t)
#pragma unroll
    for (int kk = 0; kk < 2; ++kk) {
      short8 pf = *(const short8*)(&Pl[w][c16][kk * 32 + g16 * 8]);
#pragma unroll
      for (int cs = 0; cs < 3; ++cs) {
        short8 vf = *(const short8*)(&Vb[cs * 16 + c16][kk * 32 + g16 * 8]);
        acc[cs] = mfma16(vf, pf, acc[cs]);
      }
    }
    __syncthreads();
  }

  float inv_l = 1.f / l_run;
#pragma unroll
  for (int cs = 0; cs < 3; ++cs) {
    ushort4 pk;
    pk.x = f2bf(acc[cs][0] * inv_l);
    pk.y = f2bf(acc[cs][1] * inv_l);
    pk.z = f2bf(acc[cs][2] * inv_l);
    pk.w = f2bf(acc[cs][3] * inv_l);
    *(ushort4*)(Rt + ((size_t)(b * Tn + s_lane)) * Cn + h * HD + cs * 16 + g16 * 4) = pk;
  }
}

// ---------------------------------------------------------------- launch
extern "C" void kernel_launch(void* const* d_in, const int* in_sizes, int n_in,
                              void* d_out, int out_size, void* d_ws, size_t ws_size,
                              hipStream_t stream) {
  const float* x = (const float*)d_in[0];
  const float* Wq = (const float*)d_in[1];
  const float* bq = (const float*)d_in[2];
  const float* Wk = (const float*)d_in[3];
  const float* bk = (const float*)d_in[4];
  const float* Wc = (const float*)d_in[5];
  const float* bc = (const float*)d_in[6];
  const float* Wd = (const float*)d_in[7];
  const float* bd = (const float*)d_in[8];
  const float* Wp = (const float*)d_in[9];
  const float* bp = (const float*)d_in[10];
  float* out = (float*)d_out;

  char* ws = (char*)d_ws;
  const size_t SZ = (size_t)Bn * Tn * Cn * sizeof(short);  // 3,145,728
  short* XTbf = (short*)(ws);
  short* Qt = (short*)(ws + SZ);
  short* Kt = (short*)(ws + 2 * SZ);
  short* Vc = (short*)(ws + 3 * SZ);
  short* Rt = (short*)(ws + 4 * SZ);
  short* WT = (short*)(ws + 5 * SZ);                        // 4 * 36864 shorts
  float* gbuf = (float*)(ws + 5 * SZ + 4 * 36864 * sizeof(short));

  transpose_x<<<dim3(Tn / 32, Cn / 32, Bn), 256, 0, stream>>>(x, XTbf);
  prep_w<<<dim3(Cn, 4), Cn, 0, stream>>>(Wq, Wk, Wc, Wp, WT);
  gemm192<1><<<dim3(16, 3, Bn), 256, 0, stream>>>(WT + 0 * 36864, bq, XTbf, Qt, nullptr);
  gemm192<1><<<dim3(16, 3, Bn), 256, 0, stream>>>(WT + 1 * 36864, bk, XTbf, Kt, nullptr);
  gemm192<0><<<dim3(16, 3, Bn), 256, 0, stream>>>(WT + 2 * 36864, bc, XTbf, Vc, nullptr);
  decay_g<<<dim3(Bn * Tn / 256), 256, 0, stream>>>(XTbf, Wd, bd, gbuf);
  attn<<<dim3(Tn / 64, Bn * Hn), 256, 0, stream>>>(Qt, Kt, Vc, gbuf, Rt);
  gemm192<2><<<dim3(16, 3, Bn), 256, 0, stream>>>(WT + 3 * 36864, bp, Rt, out, x);
}

// Round 3
// 115.737 us; speedup vs baseline: 1.3284x; 1.3284x over previous
//
#include <hip/hip_runtime.h>

typedef __attribute__((ext_vector_type(8))) short short8;
typedef __attribute__((ext_vector_type(4))) float f32x4;

constexpr int Bn = 4, Cn = 192, Tn = 2048, Hn = 4, HD = 48;
constexpr float LOG2E = 1.4426950408889634f;
constexpr float QK_SCALE2 = 0.14433756729740643f * 1.4426950408889634f;  // rsqrt(48)*log2e
constexpr float NEG100_LOG2 = -100.0f * 1.4426950408889634f;             // -100 in log2 domain

__device__ inline unsigned short f2bf(float f) {
  unsigned int u = __builtin_bit_cast(unsigned int, f);
  return (unsigned short)((u + 0x7FFFu + ((u >> 16) & 1u)) >> 16);
}
__device__ inline float bf2f(unsigned short h) {
  unsigned int u = ((unsigned int)h) << 16;
  return __builtin_bit_cast(float, u);
}
__device__ inline f32x4 mfma16(short8 a, short8 b, f32x4 c) {
  return __builtin_amdgcn_mfma_f32_16x16x32_bf16(a, b, c, 0, 0, 0);
}
__device__ inline unsigned int cvtpk(float lo, float hi) {
  unsigned int r;
  asm("v_cvt_pk_bf16_f32 %0, %1, %2" : "=v"(r) : "v"(lo), "v"(hi));
  return r;
}

// ---------------------------------------------------------------- transpose x
// x[b][c][t] f32  ->  XT[b][t][c] bf16
__global__ __launch_bounds__(256) void transpose_x(const float* __restrict__ x,
                                                   short* __restrict__ xt) {
  __shared__ short tile[32][40];
  int t0 = blockIdx.x * 32, c0 = blockIdx.y * 32, b = blockIdx.z;
  int tid = threadIdx.x;
  int row = tid >> 3, q = tid & 7;
  float4 v = *(const float4*)(x + ((size_t)(b * Cn + c0 + row)) * Tn + t0 + q * 4);
  tile[row][q * 4 + 0] = (short)f2bf(v.x);
  tile[row][q * 4 + 1] = (short)f2bf(v.y);
  tile[row][q * 4 + 2] = (short)f2bf(v.z);
  tile[row][q * 4 + 3] = (short)f2bf(v.w);
  __syncthreads();
  ushort4 pk;
  pk.x = (unsigned short)tile[q * 4 + 0][row];
  pk.y = (unsigned short)tile[q * 4 + 1][row];
  pk.z = (unsigned short)tile[q * 4 + 2][row];
  pk.w = (unsigned short)tile[q * 4 + 3][row];
  *(ushort4*)(xt + ((size_t)(b * Tn + t0 + row)) * Cn + c0 + q * 4) = pk;
}

// ---------------------------------------------------------------- weights
// W[k][n] f32 -> WT[j][n][k] bf16  (j = 0..3 : Wq, Wk, Wc, Wp; rows concatenated)
__global__ void prep_w(const float* __restrict__ Wq, const float* __restrict__ Wk,
                       const float* __restrict__ Wc, const float* __restrict__ Wp,
                       short* __restrict__ WT) {
  int n = blockIdx.x, j = blockIdx.y, k = threadIdx.x;
  const float* W = (j == 0) ? Wq : (j == 1) ? Wk : (j == 2) ? Wc : Wp;
  WT[((size_t)j * Cn + n) * Cn + k] = (short)f2bf(W[(size_t)k * Cn + n]);
}

// ---------------------------------------------------------------- final GEMM
// Out[n][t] = sum_k WT[n][k] * Bsrc[b][t][k] + bias[n]  -> f32 c-major + residual
__global__ __launch_bounds__(256) void gemm_out(const short* __restrict__ Awt,
                                                const float* __restrict__ bias,
                                                const short* __restrict__ Bsrc,
                                                float* __restrict__ O,
                                                const float* __restrict__ Xres) {
  constexpr int LDK = 200;
  __shared__ short As[64 * LDK];
  __shared__ short Bs[128 * LDK];
  int tt = blockIdx.x, nt = blockIdx.y, b = blockIdx.z;
  int n0 = nt * 64, t0 = tt * 128;
  int tid = threadIdx.x, w = tid >> 6, l = tid & 63;
  int g16 = l >> 4, c16 = l & 15;

  for (int idx = tid; idx < 4608; idx += 256) {
    if (idx < 1536) {
      int row = idx / 24, ch = idx % 24;
      *(float4*)(&As[row * LDK + ch * 8]) =
          *(const float4*)(Awt + ((size_t)(n0 + row)) * Cn + ch * 8);
    } else {
      int j = idx - 1536;
      int row = j / 24, ch = j % 24;
      *(float4*)(&Bs[row * LDK + ch * 8]) =
          *(const float4*)(Bsrc + ((size_t)(b * Tn + t0 + row)) * Cn + ch * 8);
    }
  }
  __syncthreads();

  f32x4 acc[4][2];
#pragma unroll
  for (int m = 0; m < 4; ++m)
#pragma unroll
    for (int n = 0; n < 2; ++n) acc[m][n] = (f32x4){0.f, 0.f, 0.f, 0.f};

#pragma unroll
  for (int kk = 0; kk < 6; ++kk) {
    short8 af[4], bf[2];
#pragma unroll
    for (int m = 0; m < 4; ++m)
      af[m] = *(const short8*)(&As[(m * 16 + c16) * LDK + kk * 32 + g16 * 8]);
#pragma unroll
    for (int n = 0; n < 2; ++n)
      bf[n] = *(const short8*)(&Bs[(w * 32 + n * 16 + c16) * LDK + kk * 32 + g16 * 8]);
#pragma unroll
    for (int m = 0; m < 4; ++m)
#pragma unroll
      for (int n = 0; n < 2; ++n) acc[m][n] = mfma16(af[m], bf[n], acc[m][n]);
  }

#pragma unroll
  for (int m = 0; m < 4; ++m)
#pragma unroll
    for (int n = 0; n < 2; ++n) {
      int nrow = n0 + m * 16 + g16 * 4;
      int tcol = t0 + w * 32 + n * 16 + c16;
#pragma unroll
      for (int r = 0; r < 4; ++r) {
        size_t i = ((size_t)(b * Cn + nrow + r)) * Tn + tcol;
        O[i] = acc[m][n][r] + bias[nrow + r] + Xres[i];
      }
    }
}

// ---------------------------------------------------------------- fused QKV GEMM
// nt 0..8 over concatenated [WqT;WkT;WcT] rows; Q,K -> t-major bf16; V -> c-major
__global__ __launch_bounds__(256) void gemm_qkv(const short* __restrict__ WT,
                                                const float* __restrict__ bq,
                                                const float* __restrict__ bk,
                                                const float* __restrict__ bc,
                                                const short* __restrict__ Bsrc,
                                                short* __restrict__ Qt,
                                                short* __restrict__ Kt,
                                                short* __restrict__ Vc) {
  constexpr int LDK = 200;
  __shared__ short As[64 * LDK];
  __shared__ short Bs[128 * LDK];
  int tt = blockIdx.x, nt = blockIdx.y, b = blockIdx.z;
  int j = nt / 3;              // 0=Q 1=K 2=V
  int ln0 = (nt - j * 3) * 64; // row within its matrix
  int n0g = nt * 64;           // row in concatenated WT
  int t0 = tt * 128;
  const float* bias = (j == 0) ? bq : (j == 1) ? bk : bc;
  int tid = threadIdx.x, w = tid >> 6, l = tid & 63;
  int g16 = l >> 4, c16 = l & 15;

  for (int idx = tid; idx < 4608; idx += 256) {
    if (idx < 1536) {
      int row = idx / 24, ch = idx % 24;
      *(float4*)(&As[row * LDK + ch * 8]) =
          *(const float4*)(WT + ((size_t)(n0g + row)) * Cn + ch * 8);
    } else {
      int jj = idx - 1536;
      int row = jj / 24, ch = jj % 24;
      *(float4*)(&Bs[row * LDK + ch * 8]) =
          *(const float4*)(Bsrc + ((size_t)(b * Tn + t0 + row)) * Cn + ch * 8);
    }
  }
  __syncthreads();

  f32x4 acc[4][2];
#pragma unroll
  for (int m = 0; m < 4; ++m)
#pragma unroll
    for (int n = 0; n < 2; ++n) acc[m][n] = (f32x4){0.f, 0.f, 0.f, 0.f};

#pragma unroll
  for (int kk = 0; kk < 6; ++kk) {
    short8 af[4], bf[2];
#pragma unroll
    for (int m = 0; m < 4; ++m)
      af[m] = *(const short8*)(&As[(m * 16 + c16) * LDK + kk * 32 + g16 * 8]);
#pragma unroll
    for (int n = 0; n < 2; ++n)
      bf[n] = *(const short8*)(&Bs[(w * 32 + n * 16 + c16) * LDK + kk * 32 + g16 * 8]);
#pragma unroll
    for (int m = 0; m < 4; ++m)
#pragma unroll
      for (int n = 0; n < 2; ++n) acc[m][n] = mfma16(af[m], bf[n], acc[m][n]);
  }

#pragma unroll
  for (int m = 0; m < 4; ++m)
#pragma unroll
    for (int n = 0; n < 2; ++n) {
      int nrow = ln0 + m * 16 + g16 * 4;
      int tcol = t0 + w * 32 + n * 16 + c16;
      if (j == 2) {
#pragma unroll
        for (int r = 0; r < 4; ++r)
          Vc[((size_t)(b * Cn + nrow + r)) * Tn + tcol] =
              (short)f2bf(acc[m][n][r] + bias[nrow + r]);
      } else {
        short* O = j ? Kt : Qt;
        ushort4 pk;
        pk.x = f2bf(acc[m][n][0] + bias[nrow + 0]);
        pk.y = f2bf(acc[m][n][1] + bias[nrow + 1]);
        pk.z = f2bf(acc[m][n][2] + bias[nrow + 2]);
        pk.w = f2bf(acc[m][n][3] + bias[nrow + 3]);
        *(ushort4*)(O + ((size_t)(b * Tn + tcol)) * Cn + nrow) = pk;
      }
    }
}

// ---------------------------------------------------------------- decay scalar
// g[b][h][t] = 0.25 * sum_f (f+1)*sigmoid( (xt@Wd + bd)[b,t,h*4+f] ); 4-way k-split
__global__ __launch_bounds__(256) void decay_g(const short* __restrict__ xt,
                                               const float* __restrict__ Wd,
                                               const float* __restrict__ bd,
                                               float* __restrict__ gout) {
  int idx = blockIdx.x * 256 + threadIdx.x;  // 32768 total
  int kq = idx & 3;
  int t = (idx >> 2) & 2047;
  int b = idx >> 13;
  const short* xr = xt + ((size_t)(b * Tn + t)) * Cn + kq * 48;
  const float* wr = Wd + kq * 48 * 16;
  float d[16];
#pragma unroll
  for (int n = 0; n < 16; ++n) d[n] = 0.f;
  for (int k = 0; k < 48; k += 8) {
    short8 xv8 = *(const short8*)(xr + k);
#pragma unroll
    for (int jj = 0; jj < 8; ++jj) {
      float xv = bf2f((unsigned short)xv8[jj]);
      const float* wrow = wr + (k + jj) * 16;
#pragma unroll
      for (int n = 0; n < 16; ++n) d[n] = fmaf(xv, wrow[n], d[n]);
    }
  }
#pragma unroll
  for (int n = 0; n < 16; ++n) {
    d[n] += __shfl_xor(d[n], 1);
    d[n] += __shfl_xor(d[n], 2);
  }
  if (kq == 0) {
#pragma unroll
    for (int h = 0; h < 4; ++h) {
      float gsum = 0.f;
#pragma unroll
      for (int f = 0; f < 4; ++f) {
        float s = 1.f / (1.f + __expf(-(d[h * 4 + f] + bd[h * 4 + f])));
        gsum += (float)(f + 1) * s;
      }
      gout[((size_t)(b * 4 + h)) * Tn + t] = 0.25f * gsum;
    }
  }
}

// ---------------------------------------------------------------- softmax scores
template <bool DIAG>
__device__ inline void score_block(const f32x4* sacc, float fb, float g2,
                                   float* sv, float& lsum) {
#pragma unroll
  for (int m = 0; m < 4; ++m) {
    float dm = fb + (float)(16 * m);
#pragma unroll
    for (int r = 0; r < 4; ++r) {
      float d = dm + (float)r;
      float ad = fabsf(d);
      float v = fmaf(-g2, ad, sacc[m][r] * QK_SCALE2);
      if constexpr (DIAG) v = (ad < 0.5f) ? NEG100_LOG2 : v;
      float e = __builtin_amdgcn_exp2f(v);
      sv[m * 4 + r] = e;
      lsum += e;
    }
  }
}

// ---------------------------------------------------------------- fused attention
// Qt,Kt: [b][t][192] bf16; Vc: [b][192][2048] bf16.
// Key-split over blockIdx.z; writes partial (acc f32, sum-exp) per query.
// LDS rows padded to 64 shorts (128B) with chunk XOR-swizzle (chunk ^= row&7).
__global__ __launch_bounds__(256, 6) void attn(const short* __restrict__ Qt,
                                               const short* __restrict__ Kt,
                                               const short* __restrict__ Vc,
                                               const float* __restrict__ gbuf,
                                               float* __restrict__ Pacc,
                                               float* __restrict__ Plsum,
                                               int kchunk) {
  __shared__ short Kb[64][64];
  __shared__ short Vb[48][64];
  __shared__ short Pl[4][16][64];
  const int s0 = blockIdx.x * 64;
  const int bh = blockIdx.y;
  const int b = bh >> 2, h = bh & 3;
  const int ks = blockIdx.z;
  const int tid = threadIdx.x, w = tid >> 6, l = tid & 63;
  const int g16 = l >> 4, c16 = l & 15;
  const int sx = c16 & 7;

  const short* Kbase = Kt + (size_t)b * Tn * Cn + h * HD;
  const short* Vbase = Vc + ((size_t)(b * Cn + h * HD)) * Tn;

  // zero logical pad chunks (6,7) of Kb once — staging never touches them
  float4 z4;
  z4.x = z4.y = z4.z = z4.w = 0.f;
  for (int idx = tid; idx < 128; idx += 256) {
    int r = idx >> 1, ch = 6 + (idx & 1);
    *(float4*)(&Kb[r][(ch ^ (r & 7)) * 8]) = z4;
  }
  // stage Q into Kb data chunks, grab fragments, then reuse Kb for K tiles
  for (int idx = tid; idx < 384; idx += 256) {
    int row = idx / 6, ch = idx % 6;
    *(float4*)(&Kb[row][(ch ^ (row & 7)) * 8]) =
        *(const float4*)(Qt + ((size_t)(b * Tn + s0 + row)) * Cn + h * HD + ch * 8);
  }
  __syncthreads();
  short8 qf[2];
  {
    int qr = w * 16 + c16;
    qf[0] = *(const short8*)(&Kb[qr][(g16 ^ sx) * 8]);
    qf[1] = *(const short8*)(&Kb[qr][((4 + g16) ^ sx) * 8]);
  }
  __syncthreads();

  const int s_lane = s0 + w * 16 + c16;
  const float g2 = gbuf[((size_t)(b * 4 + h)) * Tn + s_lane] * LOG2E;
  float lsum = 0.f;
  f32x4 acc[3];
#pragma unroll
  for (int cs = 0; cs < 3; ++cs) acc[cs] = (f32x4){0.f, 0.f, 0.f, 0.f};

  const int tend = ks * kchunk + kchunk;
  for (int t0 = ks * kchunk; t0 < tend; t0 += 64) {
    for (int idx = tid; idx < 768; idx += 256) {
      if (idx < 384) {
        int row = idx / 6, ch = idx % 6;
        *(float4*)(&Kb[row][(ch ^ (row & 7)) * 8]) =
            *(const float4*)(Kbase + ((size_t)(t0 + row)) * Cn + ch * 8);
      } else {
        int jj = idx - 384, row = jj >> 3, ch = jj & 7;
        *(float4*)(&Vb[row][(ch ^ (row & 7)) * 8]) =
            *(const float4*)(Vbase + (size_t)row * Tn + t0 + ch * 8);
      }
    }
    __syncthreads();

    // S = K_tile^T . Q
    f32x4 sacc[4];
#pragma unroll
    for (int m = 0; m < 4; ++m) sacc[m] = (f32x4){0.f, 0.f, 0.f, 0.f};
#pragma unroll
    for (int kk = 0; kk < 2; ++kk)
#pragma unroll
      for (int m = 0; m < 4; ++m) {
        short8 af = *(const short8*)(&Kb[m * 16 + c16][((kk * 4 + g16) ^ sx) * 8]);
        sacc[m] = mfma16(af, qf[kk], sacc[m]);
      }

    // logits (log2 domain), no running max: exp2 directly, accumulate per-lane sum
    float sv[16];
    const float fb = (float)(t0 + g16 * 4 - s_lane);
    if (t0 == s0)
      score_block<true>(sacc, fb, g2, sv, lsum);
    else
      score_block<false>(sacc, fb, g2, sv, lsum);

    // P -> wave-private LDS (swizzled), one b64 per m
#pragma unroll
    for (int m = 0; m < 4; ++m) {
      unsigned int u0 = cvtpk(sv[m * 4 + 0], sv[m * 4 + 1]);
      unsigned int u1 = cvtpk(sv[m * 4 + 2], sv[m * 4 + 3]);
      unsigned long long u64v = ((unsigned long long)u1 << 32) | (unsigned long long)u0;
      *(unsigned long long*)(&Pl[w][c16][(((2 * m + (g16 >> 1)) ^ sx) * 8) + (g16 & 1) * 4]) =
          u64v;
    }
    asm volatile("s_waitcnt lgkmcnt(0)" ::: "memory");

    // O += V_tile . P
#pragma unroll
    for (int kk = 0; kk < 2; ++kk) {
      short8 pf = *(const short8*)(&Pl[w][c16][((kk * 4 + g16) ^ sx) * 8]);
#pragma unroll
      for (int cs = 0; cs < 3; ++cs) {
        short8 vf = *(const short8*)(&Vb[cs * 16 + c16][((kk * 4 + g16) ^ sx) * 8]);
        acc[cs] = mfma16(vf, pf, acc[cs]);
      }
    }
    __syncthreads();
  }

  lsum += __shfl_xor(lsum, 16);
  lsum += __shfl_xor(lsum, 32);
  const size_t qb = ((size_t)(ks * 16 + bh)) * Tn + s_lane;
  float* pa = Pacc + qb * 48 + g16 * 4;
#pragma unroll
  for (int cs = 0; cs < 3; ++cs) *(f32x4*)(pa + cs * 16) = acc[cs];
  if (g16 == 0) Plsum[qb] = lsum;
}

// ---------------------------------------------------------------- combine partials
// Rt[b][s][c] bf16 = (sum_ks acc) / (sum_ks l)
__global__ __launch_bounds__(256) void combine(const float* __restrict__ Pacc,
                                               const float* __restrict__ Plsum,
                                               short* __restrict__ Rt, int KS) {
  int idx = blockIdx.x * 256 + threadIdx.x;  // 4*2048*48
  int c4 = idx % 48;
  int rest = idx / 48;
  int s = rest & 2047;
  int b = rest >> 11;
  int c = c4 * 4;
  int h = c / 48;
  int cc = c - h * 48;
  size_t qb = ((size_t)(b * 4 + h)) * Tn + s;
  float a0 = 0.f, a1 = 0.f, a2 = 0.f, a3 = 0.f, lt = 0.f;
  for (int ks = 0; ks < KS; ++ks) {
    const float* p = Pacc + ((size_t)ks * 16 * Tn + qb) * 48 + cc;
    float4 v = *(const float4*)p;
    a0 += v.x;
    a1 += v.y;
    a2 += v.z;
    a3 += v.w;
    lt += Plsum[(size_t)ks * 16 * Tn + qb];
  }
  float inv = 1.f / lt;
  ushort4 pk;
  pk.x = f2bf(a0 * inv);
  pk.y = f2bf(a1 * inv);
  pk.z = f2bf(a2 * inv);
  pk.w = f2bf(a3 * inv);
  *(ushort4*)(Rt + ((size_t)(b * Tn + s)) * Cn + c) = pk;
}

// ---------------------------------------------------------------- launch
extern "C" void kernel_launch(void* const* d_in, const int* in_sizes, int n_in,
                              void* d_out, int out_size, void* d_ws, size_t ws_size,
                              hipStream_t stream) {
  const float* x = (const float*)d_in[0];
  const float* Wq = (const float*)d_in[1];
  const float* bq = (const float*)d_in[2];
  const float* Wk = (const float*)d_in[3];
  const float* bk = (const float*)d_in[4];
  const float* Wc = (const float*)d_in[5];
  const float* bc = (const float*)d_in[6];
  const float* Wd = (const float*)d_in[7];
  const float* bd = (const float*)d_in[8];
  const float* Wp = (const float*)d_in[9];
  const float* bp = (const float*)d_in[10];
  float* out = (float*)d_out;

  char* ws = (char*)d_ws;
  const size_t SZ = (size_t)Bn * Tn * Cn * sizeof(short);  // 3,145,728
  short* XTbf = (short*)(ws);
  short* Qt = (short*)(ws + SZ);
  short* Kt = (short*)(ws + 2 * SZ);
  short* Vc = (short*)(ws + 3 * SZ);
  short* Rt = (short*)(ws + 4 * SZ);
  short* WT = (short*)(ws + 5 * SZ);  // 4*192*192 shorts = 294912 B
  float* gbuf = (float*)(ws + 5 * SZ + 294912);
  char* pbase = ws + 5 * SZ + 294912 + 131072;

  const size_t base = 5 * SZ + 294912 + 131072;
  const size_t perks = (size_t)16 * Tn * 48 * 4 + (size_t)16 * Tn * 4;
  int KS = 4;
  if (ws_size && base + 4 * perks > ws_size) KS = (base + 2 * perks <= ws_size) ? 2 : 1;
  float* Pacc = (float*)pbase;
  float* Plsum = (float*)(pbase + (size_t)KS * 16 * Tn * 48 * 4);

  transpose_x<<<dim3(Tn / 32, Cn / 32, Bn), 256, 0, stream>>>(x, XTbf);
  prep_w<<<dim3(Cn, 4), Cn, 0, stream>>>(Wq, Wk, Wc, Wp, WT);
  gemm_qkv<<<dim3(16, 9, Bn), 256, 0, stream>>>(WT, bq, bk, bc, XTbf, Qt, Kt, Vc);
  decay_g<<<dim3(128), 256, 0, stream>>>(XTbf, Wd, bd, gbuf);
  attn<<<dim3(Tn / 64, Bn * Hn, KS), 256, 0, stream>>>(Qt, Kt, Vc, gbuf, Pacc, Plsum,
                                                       Tn / KS);
  combine<<<dim3(Bn * Tn * 48 / 256), 256, 0, stream>>>(Pacc, Plsum, Rt, KS);
  gemm_out<<<dim3(16, 3, Bn), 256, 0, stream>>>(WT + 3 * 36864, bp, Rt, out, x);
}

// Round 5
// 113.143 us; speedup vs baseline: 1.3588x; 1.0229x over previous
//
#include <hip/hip_runtime.h>

typedef __attribute__((ext_vector_type(8))) short short8;
typedef __attribute__((ext_vector_type(4))) float f32x4;

constexpr int Bn = 4, Cn = 192, Tn = 2048, Hn = 4, HD = 48;
constexpr float LOG2E = 1.4426950408889634f;
constexpr float QK_SCALE2 = 0.14433756729740643f * 1.4426950408889634f;  // rsqrt(48)*log2e
constexpr float NEG100_LOG2 = -100.0f * 1.4426950408889634f;

__device__ inline unsigned short f2bf(float f) {
  unsigned int u = __builtin_bit_cast(unsigned int, f);
  return (unsigned short)((u + 0x7FFFu + ((u >> 16) & 1u)) >> 16);
}
__device__ inline float bf2f(unsigned short h) {
  unsigned int u = ((unsigned int)h) << 16;
  return __builtin_bit_cast(float, u);
}
__device__ inline f32x4 mfma16(short8 a, short8 b, f32x4 c) {
  return __builtin_amdgcn_mfma_f32_16x16x32_bf16(a, b, c, 0, 0, 0);
}
__device__ inline unsigned int cvtpk(float lo, float hi) {
  unsigned int r;
  asm("v_cvt_pk_bf16_f32 %0, %1, %2" : "=v"(r) : "v"(lo), "v"(hi));
  return r;
}

// ---------------------------------------------------------------- transpose x
// x[b][c][t] f32  ->  XT[b][t][c] bf16
__global__ __launch_bounds__(256) void transpose_x(const float* __restrict__ x,
                                                   short* __restrict__ xt) {
  __shared__ short tile[32][40];
  int t0 = blockIdx.x * 32, c0 = blockIdx.y * 32, b = blockIdx.z;
  int tid = threadIdx.x;
  int row = tid >> 3, q = tid & 7;
  float4 v = *(const float4*)(x + ((size_t)(b * Cn + c0 + row)) * Tn + t0 + q * 4);
  tile[row][q * 4 + 0] = (short)f2bf(v.x);
  tile[row][q * 4 + 1] = (short)f2bf(v.y);
  tile[row][q * 4 + 2] = (short)f2bf(v.z);
  tile[row][q * 4 + 3] = (short)f2bf(v.w);
  __syncthreads();
  ushort4 pk;
  pk.x = (unsigned short)tile[q * 4 + 0][row];
  pk.y = (unsigned short)tile[q * 4 + 1][row];
  pk.z = (unsigned short)tile[q * 4 + 2][row];
  pk.w = (unsigned short)tile[q * 4 + 3][row];
  *(ushort4*)(xt + ((size_t)(b * Tn + t0 + row)) * Cn + c0 + q * 4) = pk;
}

// ---------------------------------------------------------------- weights
// W[k][n] f32 -> WT[j][n][k] bf16  (j = 0..3 : Wq, Wk, Wc, Wp; rows concatenated)
__global__ void prep_w(const float* __restrict__ Wq, const float* __restrict__ Wk,
                       const float* __restrict__ Wc, const float* __restrict__ Wp,
                       short* __restrict__ WT) {
  int n = blockIdx.x, j = blockIdx.y, k = threadIdx.x;
  const float* W = (j == 0) ? Wq : (j == 1) ? Wk : (j == 2) ? Wc : Wp;
  WT[((size_t)j * Cn + n) * Cn + k] = (short)f2bf(W[(size_t)k * Cn + n]);
}

// ---------------------------------------------------------------- final GEMM
__global__ __launch_bounds__(256) void gemm_out(const short* __restrict__ Awt,
                                                const float* __restrict__ bias,
                                                const short* __restrict__ Bsrc,
                                                float* __restrict__ O,
                                                const float* __restrict__ Xres) {
  constexpr int LDK = 200;
  __shared__ short As[64 * LDK];
  __shared__ short Bs[128 * LDK];
  int tt = blockIdx.x, nt = blockIdx.y, b = blockIdx.z;
  int n0 = nt * 64, t0 = tt * 128;
  int tid = threadIdx.x, w = tid >> 6, l = tid & 63;
  int g16 = l >> 4, c16 = l & 15;

  for (int idx = tid; idx < 4608; idx += 256) {
    if (idx < 1536) {
      int row = idx / 24, ch = idx % 24;
      *(float4*)(&As[row * LDK + ch * 8]) =
          *(const float4*)(Awt + ((size_t)(n0 + row)) * Cn + ch * 8);
    } else {
      int j = idx - 1536;
      int row = j / 24, ch = j % 24;
      *(float4*)(&Bs[row * LDK + ch * 8]) =
          *(const float4*)(Bsrc + ((size_t)(b * Tn + t0 + row)) * Cn + ch * 8);
    }
  }
  __syncthreads();

  f32x4 acc[4][2];
#pragma unroll
  for (int m = 0; m < 4; ++m)
#pragma unroll
    for (int n = 0; n < 2; ++n) acc[m][n] = (f32x4){0.f, 0.f, 0.f, 0.f};

#pragma unroll
  for (int kk = 0; kk < 6; ++kk) {
    short8 af[4], bf[2];
#pragma unroll
    for (int m = 0; m < 4; ++m)
      af[m] = *(const short8*)(&As[(m * 16 + c16) * LDK + kk * 32 + g16 * 8]);
#pragma unroll
    for (int n = 0; n < 2; ++n)
      bf[n] = *(const short8*)(&Bs[(w * 32 + n * 16 + c16) * LDK + kk * 32 + g16 * 8]);
#pragma unroll
    for (int m = 0; m < 4; ++m)
#pragma unroll
      for (int n = 0; n < 2; ++n) acc[m][n] = mfma16(af[m], bf[n], acc[m][n]);
  }

#pragma unroll
  for (int m = 0; m < 4; ++m)
#pragma unroll
    for (int n = 0; n < 2; ++n) {
      int nrow = n0 + m * 16 + g16 * 4;
      int tcol = t0 + w * 32 + n * 16 + c16;
#pragma unroll
      for (int r = 0; r < 4; ++r) {
        size_t i = ((size_t)(b * Cn + nrow + r)) * Tn + tcol;
        O[i] = acc[m][n][r] + bias[nrow + r] + Xres[i];
      }
    }
}

// ---------------------------------------------------------------- fused QKV GEMM
// nt 0..8 over concatenated [WqT;WkT;WcT] rows; Q,K -> t-major bf16; V -> c-major
__global__ __launch_bounds__(256) void gemm_qkv(const short* __restrict__ WT,
                                                const float* __restrict__ bq,
                                                const float* __restrict__ bk,
                                                const float* __restrict__ bc,
                                                const short* __restrict__ Bsrc,
                                                short* __restrict__ Qt,
                                                short* __restrict__ Kt,
                                                short* __restrict__ Vc) {
  constexpr int LDK = 200;
  __shared__ short As[64 * LDK];
  __shared__ short Bs[128 * LDK];
  int tt = blockIdx.x, nt = blockIdx.y, b = blockIdx.z;
  int j = nt / 3;              // 0=Q 1=K 2=V
  int ln0 = (nt - j * 3) * 64; // row within its matrix
  int n0g = nt * 64;           // row in concatenated WT
  int t0 = tt * 128;
  const float* bias = (j == 0) ? bq : (j == 1) ? bk : bc;
  int tid = threadIdx.x, w = tid >> 6, l = tid & 63;
  int g16 = l >> 4, c16 = l & 15;

  for (int idx = tid; idx < 4608; idx += 256) {
    if (idx < 1536) {
      int row = idx / 24, ch = idx % 24;
      *(float4*)(&As[row * LDK + ch * 8]) =
          *(const float4*)(WT + ((size_t)(n0g + row)) * Cn + ch * 8);
    } else {
      int jj = idx - 1536;
      int row = jj / 24, ch = jj % 24;
      *(float4*)(&Bs[row * LDK + ch * 8]) =
          *(const float4*)(Bsrc + ((size_t)(b * Tn + t0 + row)) * Cn + ch * 8);
    }
  }
  __syncthreads();

  f32x4 acc[4][2];
#pragma unroll
  for (int m = 0; m < 4; ++m)
#pragma unroll
    for (int n = 0; n < 2; ++n) acc[m][n] = (f32x4){0.f, 0.f, 0.f, 0.f};

#pragma unroll
  for (int kk = 0; kk < 6; ++kk) {
    short8 af[4], bf[2];
#pragma unroll
    for (int m = 0; m < 4; ++m)
      af[m] = *(const short8*)(&As[(m * 16 + c16) * LDK + kk * 32 + g16 * 8]);
#pragma unroll
    for (int n = 0; n < 2; ++n)
      bf[n] = *(const short8*)(&Bs[(w * 32 + n * 16 + c16) * LDK + kk * 32 + g16 * 8]);
#pragma unroll
    for (int m = 0; m < 4; ++m)
#pragma unroll
      for (int n = 0; n < 2; ++n) acc[m][n] = mfma16(af[m], bf[n], acc[m][n]);
  }

#pragma unroll
  for (int m = 0; m < 4; ++m)
#pragma unroll
    for (int n = 0; n < 2; ++n) {
      int nrow = ln0 + m * 16 + g16 * 4;
      int tcol = t0 + w * 32 + n * 16 + c16;
      if (j == 2) {
#pragma unroll
        for (int r = 0; r < 4; ++r)
          Vc[((size_t)(b * Cn + nrow + r)) * Tn + tcol] =
              (short)f2bf(acc[m][n][r] + bias[nrow + r]);
      } else {
        short* O = j ? Kt : Qt;
        ushort4 pk;
        pk.x = f2bf(acc[m][n][0] + bias[nrow + 0]);
        pk.y = f2bf(acc[m][n][1] + bias[nrow + 1]);
        pk.z = f2bf(acc[m][n][2] + bias[nrow + 2]);
        pk.w = f2bf(acc[m][n][3] + bias[nrow + 3]);
        *(ushort4*)(O + ((size_t)(b * Tn + tcol)) * Cn + nrow) = pk;
      }
    }
}

// ---------------------------------------------------------------- decay scalar
// g[b][h][t] = 0.25 * sum_f (f+1)*sigmoid( (xt@Wd + bd)[b,t,h*4+f] ); 4-way k-split
__global__ __launch_bounds__(256) void decay_g(const short* __restrict__ xt,
                                               const float* __restrict__ Wd,
                                               const float* __restrict__ bd,
                                               float* __restrict__ gout) {
  int idx = blockIdx.x * 256 + threadIdx.x;  // 32768 total
  int kq = idx & 3;
  int t = (idx >> 2) & 2047;
  int b = idx >> 13;
  const short* xr = xt + ((size_t)(b * Tn + t)) * Cn + kq * 48;
  const float* wr = Wd + kq * 48 * 16;
  float d[16];
#pragma unroll
  for (int n = 0; n < 16; ++n) d[n] = 0.f;
  for (int k = 0; k < 48; k += 8) {
    short8 xv8 = *(const short8*)(xr + k);
#pragma unroll
    for (int jj = 0; jj < 8; ++jj) {
      float xv = bf2f((unsigned short)xv8[jj]);
      const float* wrow = wr + (k + jj) * 16;
#pragma unroll
      for (int n = 0; n < 16; ++n) d[n] = fmaf(xv, wrow[n], d[n]);
    }
  }
#pragma unroll
  for (int n = 0; n < 16; ++n) {
    d[n] += __shfl_xor(d[n], 1);
    d[n] += __shfl_xor(d[n], 2);
  }
  if (kq == 0) {
#pragma unroll
    for (int h = 0; h < 4; ++h) {
      float gsum = 0.f;
#pragma unroll
      for (int f = 0; f < 4; ++f) {
        float s = 1.f / (1.f + __expf(-(d[h * 4 + f] + bd[h * 4 + f])));
        gsum += (float)(f + 1) * s;
      }
      gout[((size_t)(b * 4 + h)) * Tn + t] = 0.25f * gsum;
    }
  }
}

// ---------------------------------------------------------------- softmax scores
template <bool DIAG>
__device__ inline void score_block(const f32x4* sacc, float fb, float g2,
                                   float* sv, float& lsum) {
#pragma unroll
  for (int m = 0; m < 4; ++m) {
    float dm = fb + (float)(16 * m);
#pragma unroll
    for (int r = 0; r < 4; ++r) {
      float d = dm + (float)r;
      float ad = fabsf(d);
      float v = fmaf(-g2, ad, sacc[m][r] * QK_SCALE2);
      if constexpr (DIAG) v = (ad < 0.5f) ? NEG100_LOG2 : v;
      float e = __builtin_amdgcn_exp2f(v);
      sv[m * 4 + r] = e;
      lsum += e;
    }
  }
}

// ---------------------------------------------------------------- fused attention
// Key-split over blockIdx.z; partials: Pacc bf16 [ks][bh][s][48], Plsum f32.
__global__ __launch_bounds__(256, 6) void attn(const short* __restrict__ Qt,
                                               const short* __restrict__ Kt,
                                               const short* __restrict__ Vc,
                                               const float* __restrict__ gbuf,
                                               unsigned short* __restrict__ Pacc,
                                               float* __restrict__ Plsum,
                                               int kchunk) {
  __shared__ short Kb[64][64];
  __shared__ short Vb[48][64];
  __shared__ short Pl[4][16][64];
  const int s0 = blockIdx.x * 64;
  const int bh = blockIdx.y;
  const int b = bh >> 2, h = bh & 3;
  const int ks = blockIdx.z;
  const int tid = threadIdx.x, w = tid >> 6, l = tid & 63;
  const int g16 = l >> 4, c16 = l & 15;
  const int sx = c16 & 7;

  const short* Kbase = Kt + (size_t)b * Tn * Cn + h * HD;
  const short* Vbase = Vc + ((size_t)(b * Cn + h * HD)) * Tn;

  // zero logical pad chunks (6,7) of Kb once — staging never touches them
  float4 z4;
  z4.x = z4.y = z4.z = z4.w = 0.f;
  for (int idx = tid; idx < 128; idx += 256) {
    int r = idx >> 1, ch = 6 + (idx & 1);
    *(float4*)(&Kb[r][(ch ^ (r & 7)) * 8]) = z4;
  }
  // stage Q into Kb data chunks, grab fragments, then reuse Kb for K tiles
  for (int idx = tid; idx < 384; idx += 256) {
    int row = idx / 6, ch = idx % 6;
    *(float4*)(&Kb[row][(ch ^ (row & 7)) * 8]) =
        *(const float4*)(Qt + ((size_t)(b * Tn + s0 + row)) * Cn + h * HD + ch * 8);
  }
  __syncthreads();
  short8 qf[2];
  {
    int qr = w * 16 + c16;
    qf[0] = *(const short8*)(&Kb[qr][(g16 ^ sx) * 8]);
    qf[1] = *(const short8*)(&Kb[qr][((4 + g16) ^ sx) * 8]);
  }
  __syncthreads();

  const int s_lane = s0 + w * 16 + c16;
  const float g2 = gbuf[((size_t)(b * 4 + h)) * Tn + s_lane] * LOG2E;
  float lsum = 0.f;
  f32x4 acc[3];
#pragma unroll
  for (int cs = 0; cs < 3; ++cs) acc[cs] = (f32x4){0.f, 0.f, 0.f, 0.f};

  const int tend = ks * kchunk + kchunk;
  for (int t0 = ks * kchunk; t0 < tend; t0 += 64) {
    for (int idx = tid; idx < 768; idx += 256) {
      if (idx < 384) {
        int row = idx / 6, ch = idx % 6;
        *(float4*)(&Kb[row][(ch ^ (row & 7)) * 8]) =
            *(const float4*)(Kbase + ((size_t)(t0 + row)) * Cn + ch * 8);
      } else {
        int jj = idx - 384, row = jj >> 3, ch = jj & 7;
        *(float4*)(&Vb[row][(ch ^ (row & 7)) * 8]) =
            *(const float4*)(Vbase + (size_t)row * Tn + t0 + ch * 8);
      }
    }
    __syncthreads();

    // S = K_tile^T . Q
    f32x4 sacc[4];
#pragma unroll
    for (int m = 0; m < 4; ++m) sacc[m] = (f32x4){0.f, 0.f, 0.f, 0.f};
#pragma unroll
    for (int kk = 0; kk < 2; ++kk)
#pragma unroll
      for (int m = 0; m < 4; ++m) {
        short8 af = *(const short8*)(&Kb[m * 16 + c16][((kk * 4 + g16) ^ sx) * 8]);
        sacc[m] = mfma16(af, qf[kk], sacc[m]);
      }

    // logits (log2 domain), no running max: exp2 directly, accumulate per-lane sum
    float sv[16];
    const float fb = (float)(t0 + g16 * 4 - s_lane);
    if (t0 == s0)
      score_block<true>(sacc, fb, g2, sv, lsum);
    else
      score_block<false>(sacc, fb, g2, sv, lsum);

    // P -> wave-private LDS (swizzled), one b64 per m
#pragma unroll
    for (int m = 0; m < 4; ++m) {
      unsigned int u0 = cvtpk(sv[m * 4 + 0], sv[m * 4 + 1]);
      unsigned int u1 = cvtpk(sv[m * 4 + 2], sv[m * 4 + 3]);
      unsigned long long u64v = ((unsigned long long)u1 << 32) | (unsigned long long)u0;
      *(unsigned long long*)(&Pl[w][c16][(((2 * m + (g16 >> 1)) ^ sx) * 8) + (g16 & 1) * 4]) =
          u64v;
    }
    asm volatile("s_waitcnt lgkmcnt(0)" ::: "memory");

    // O += V_tile . P
#pragma unroll
    for (int kk = 0; kk < 2; ++kk) {
      short8 pf = *(const short8*)(&Pl[w][c16][((kk * 4 + g16) ^ sx) * 8]);
#pragma unroll
      for (int cs = 0; cs < 3; ++cs) {
        short8 vf = *(const short8*)(&Vb[cs * 16 + c16][((kk * 4 + g16) ^ sx) * 8]);
        acc[cs] = mfma16(vf, pf, acc[cs]);
      }
    }
    __syncthreads();
  }

  float lsum2 = lsum + __shfl_xor(lsum, 16);
  lsum2 += __shfl_xor(lsum2, 32);
  if (g16 == 0) Plsum[((size_t)(ks * 16 + bh)) * Tn + s_lane] = lsum2;

  // bounce acc -> LDS (bf16, reuse Kb) then coalesced contiguous global store
  unsigned int* Ob = (unsigned int*)&Kb[0][0];  // [64][24] u32 = 6144 B <= 8192 B
  const int orow = w * 16 + c16;
#pragma unroll
  for (int cs = 0; cs < 3; ++cs) {
    Ob[orow * 24 + cs * 8 + g16 * 2 + 0] = cvtpk(acc[cs][0], acc[cs][1]);
    Ob[orow * 24 + cs * 8 + g16 * 2 + 1] = cvtpk(acc[cs][2], acc[cs][3]);
  }
  __syncthreads();
  float4* dst = (float4*)(Pacc + (((size_t)(ks * 16 + bh)) * Tn + s0) * 48);
  const float4* src = (const float4*)Ob;
  dst[tid] = src[tid];
  if (tid < 128) dst[tid + 256] = src[tid + 256];
}

// ---------------------------------------------------------------- combine partials
__global__ __launch_bounds__(256) void combine(const unsigned short* __restrict__ Pacc,
                                               const float* __restrict__ Plsum,
                                               short* __restrict__ Rt, int KS) {
  int idx = blockIdx.x * 256 + threadIdx.x;  // Bn*Tn*48
  int c4 = idx % 48;
  int rest = idx / 48;
  int s = rest & 2047;
  int b = rest >> 11;
  int c = c4 * 4;
  int h = c / 48;
  int cc = c - h * 48;
  size_t qb = ((size_t)(b * 4 + h)) * Tn + s;
  float a0 = 0.f, a1 = 0.f, a2 = 0.f, a3 = 0.f, lt = 0.f;
  for (int ks = 0; ks < KS; ++ks) {
    ushort4 v = *(const ushort4*)(Pacc + ((size_t)ks * 16 * Tn + qb) * 48 + cc);
    a0 += bf2f(v.x);
    a1 += bf2f(v.y);
    a2 += bf2f(v.z);
    a3 += bf2f(v.w);
    lt += Plsum[(size_t)ks * 16 * Tn + qb];
  }
  float inv = 1.f / lt;
  ushort4 pk;
  pk.x = f2bf(a0 * inv);
  pk.y = f2bf(a1 * inv);
  pk.z = f2bf(a2 * inv);
  pk.w = f2bf(a3 * inv);
  *(ushort4*)(Rt + ((size_t)(b * Tn + s)) * Cn + c) = pk;
}

// ---------------------------------------------------------------- launch
extern "C" void kernel_launch(void* const* d_in, const int* in_sizes, int n_in,
                              void* d_out, int out_size, void* d_ws, size_t ws_size,
                              hipStream_t stream) {
  const float* x = (const float*)d_in[0];
  const float* Wq = (const float*)d_in[1];
  const float* bq = (const float*)d_in[2];
  const float* Wk = (const float*)d_in[3];
  const float* bk = (const float*)d_in[4];
  const float* Wc = (const float*)d_in[5];
  const float* bc = (const float*)d_in[6];
  const float* Wd = (const float*)d_in[7];
  const float* bd = (const float*)d_in[8];
  const float* Wp = (const float*)d_in[9];
  const float* bp = (const float*)d_in[10];
  float* out = (float*)d_out;

  char* ws = (char*)d_ws;
  const size_t SZ = (size_t)Bn * Tn * Cn * sizeof(short);  // 3,145,728
  short* XTbf = (short*)(ws);
  short* Qt = (short*)(ws + SZ);
  short* Kt = (short*)(ws + 2 * SZ);
  short* Vc = (short*)(ws + 3 * SZ);
  short* Rt = (short*)(ws + 4 * SZ);
  short* WT = (short*)(ws + 5 * SZ);  // 4*192*192 shorts = 294912 B
  float* gbuf = (float*)(ws + 5 * SZ + 294912);
  char* pbase = ws + 5 * SZ + 294912 + 131072;

  const size_t base = 5 * SZ + 294912 + 131072;
  const size_t perks = (size_t)16 * Tn * 48 * 2 + (size_t)16 * Tn * 4;  // 3,276,800
  int KS = 8;
  if (ws_size && base + 8 * perks > ws_size)
    KS = (base + 4 * perks <= ws_size) ? 4 : ((base + 2 * perks <= ws_size) ? 2 : 1);
  unsigned short* Pacc = (unsigned short*)pbase;
  float* Plsum = (float*)(pbase + (size_t)KS * 16 * Tn * 48 * 2);

  transpose_x<<<dim3(Tn / 32, Cn / 32, Bn), 256, 0, stream>>>(x, XTbf);
  prep_w<<<dim3(Cn, 4), Cn, 0, stream>>>(Wq, Wk, Wc, Wp, WT);
  gemm_qkv<<<dim3(16, 9, Bn), 256, 0, stream>>>(WT, bq, bk, bc, XTbf, Qt, Kt, Vc);
  decay_g<<<dim3(128), 256, 0, stream>>>(XTbf, Wd, bd, gbuf);
  attn<<<dim3(Tn / 64, Bn * Hn, KS), 256, 0, stream>>>(Qt, Kt, Vc, gbuf, Pacc, Plsum,
                                                       Tn / KS);
  combine<<<dim3(Bn * Tn * 48 / 256), 256, 0, stream>>>(Pacc, Plsum, Rt, KS);
  gemm_out<<<dim3(16, 3, Bn), 256, 0, stream>>>(WT + 3 * 36864, bp, Rt, out, x);
}